// Round 8
// baseline (1385.878 us; speedup 1.0000x reference)
//
#include <hip/hip_runtime.h>

#define T_LEN 4096
#define B_SZ  256

typedef float v2f __attribute__((ext_vector_type(2)));
typedef float v4f __attribute__((ext_vector_type(4)));

__device__ __forceinline__ float fexp2(float x) { return __builtin_amdgcn_exp2f(x); }
__device__ __forceinline__ float frcp(float x)  { return __builtin_amdgcn_rcpf(x); }

// DPP row_ror:S (S=1..15): lane l <- lane (l-S)&15 within its 16-lane row.
template<int S>
__device__ __forceinline__ float rorN(float v) {
    return __int_as_float(__builtin_amdgcn_update_dpp(
        0, __float_as_int(v), 0x120 + S, 0xf, 0xf, true));
}

// Inline-asm vm ops: RA cannot rematerialize an asm result (plain loads were
// re-emitted at uses, exposing full latency), and the asm vm stream keeps
// the outstanding-op counts for manual s_waitcnt exact.
template<int OFF>
__device__ __forceinline__ v4f aload(const float* p) {
    v4f r;
    asm volatile("global_load_dwordx4 %0, %1, off offset:%2"
                 : "=v"(r) : "v"(p), "i"(OFF) : "memory");
    return r;
}
__device__ __forceinline__ void aatomic(float* p, float v) {
    unsafeAtomicAdd(p, v);   // global_atomic_add_f32, no-return (result dead)
}
__device__ __forceinline__ void astore(float* p, float v) {
    asm volatile("global_store_dword %0, %1, off" :: "v"(p), "v"(v) : "memory");
}

// ---------------------------------------------------------------------------
// Fallback-path init: y1 <- bl1 broadcast, out <- bl2 broadcast.
// ---------------------------------------------------------------------------
__global__ void init_bias_kernel(const float* __restrict__ bl1,
                                 const float* __restrict__ bl2,
                                 float* __restrict__ y1,
                                 float* __restrict__ out)
{
    const long idx = (long)blockIdx.x * blockDim.x + threadIdx.x; // over B*T
    float4 a1 = make_float4(bl1[0], bl1[1], bl1[2], bl1[3]);
    float4 b1 = make_float4(bl1[4], bl1[5], bl1[6], bl1[7]);
    float4 a2 = make_float4(bl2[0], bl2[1], bl2[2], bl2[3]);
    float4 b2 = make_float4(bl2[4], bl2[5], bl2[6], bl2[7]);
    float4* y4 = (float4*)y1;
    float4* o4 = (float4*)out;
    y4[idx * 2 + 0] = a1;
    y4[idx * 2 + 1] = b1;
    o4[idx * 2 + 0] = a2;
    o4[idx * 2 + 1] = b2;
}

// ---------------------------------------------------------------------------
// Dense output projection y[b,t,:] = Hf@Wf^T + Hb@Wb^T + bl. One thread per
// (b,t) row. Hb/yo may ALIAS (final kernel runs in-place over d_out) -> no
// __restrict__ on those two; loads are emitted before stores (own row only).
// ---------------------------------------------------------------------------
__global__ void proj_kernel(const float* __restrict__ Hf,
                            const float* Hb,
                            const float* __restrict__ W,   // [8,16]
                            const float* __restrict__ bl,  // [8]
                            float* yo)
{
    const long idx = (long)blockIdx.x * blockDim.x + threadIdx.x; // over B*T
    const float4* f4 = (const float4*)(Hf + idx * 8);
    const float4* b4 = (const float4*)(Hb + idx * 8);
    float4 fa = f4[0], fb = f4[1];
    float4 ba = b4[0], bb = b4[1];
    float o[8];
    #pragma unroll
    for (int d = 0; d < 8; ++d) {
        float s = bl[d];
        s = fmaf(fa.x, W[d * 16 + 0], s);
        s = fmaf(fa.y, W[d * 16 + 1], s);
        s = fmaf(fa.z, W[d * 16 + 2], s);
        s = fmaf(fa.w, W[d * 16 + 3], s);
        s = fmaf(fb.x, W[d * 16 + 4], s);
        s = fmaf(fb.y, W[d * 16 + 5], s);
        s = fmaf(fb.z, W[d * 16 + 6], s);
        s = fmaf(fb.w, W[d * 16 + 7], s);
        s = fmaf(ba.x, W[d * 16 + 8], s);
        s = fmaf(ba.y, W[d * 16 + 9], s);
        s = fmaf(ba.z, W[d * 16 + 10], s);
        s = fmaf(ba.w, W[d * 16 + 11], s);
        s = fmaf(bb.x, W[d * 16 + 12], s);
        s = fmaf(bb.y, W[d * 16 + 13], s);
        s = fmaf(bb.z, W[d * 16 + 14], s);
        s = fmaf(bb.w, W[d * 16 + 15], s);
        o[d] = s;
    }
    float4* y4 = (float4*)(yo + idx * 8);
    y4[0] = make_float4(o[0], o[1], o[2], o[3]);
    y4[1] = make_float4(o[4], o[5], o[6], o[7]);
}

// ---------------------------------------------------------------------------
// Recurrence, one direction (ST=+1 fwd / -1 bwd). 16 lanes per cell; lane
// cl: unit j=cl&7, half=cl>>3. Each lane computes TWO gate rows packed
// <2 x float>: half0 -> (i_j, f_j), half1 -> (g_j, o_j). h is period-8
// replicated over the 16-lane row; DPP row_ror does the h broadcast. x
// arrives through an asm-load register ring (3 macros of 4 steps),
// lookahead 2 macros, exact manual s_waitcnt vmcnt(N).
//
// THIS ROUND — exec-half-skip experiment: waves carry 2 cells in lanes
// 0..31; lanes 32..63 exit up front so the UPPER 32-lane half of every
// VALU/trans op is fully inactive. If gfx950 skips fully-masked halves,
// wave64 VALU issue drops 2->1 cyc and quarter-rate trans 8->4 cyc
// (~halves the ~122 cyc/step issue component) with arithmetic unchanged.
// Grid doubles to 256 blocks (1/CU, still 1 wave/SIMD, no contention).
// Step body, ring, and vmcnt ledger are byte-identical to the proven
// 1068-us tier-B configuration.
//
// PROJ=true (fused fallback): atomic-add projection of h_{t-1}, ramp
// 16/19/23, steady 24, tail projects final h. PROJ=false: one plain
// global_store_dword of h_t per step (both halves store identical value:
// benign duplicate), ramp 16/20/24, steady 24.
// ---------------------------------------------------------------------------
template<int ST, bool PROJ>
__device__ __forceinline__ void rec_body(
    const float* x, const float* Wih, const float* Whh, const float* bias,
    const float* Wp, int dcol, float* y, float* H, int b0)
{
    const int tid  = threadIdx.x;
    const int cl   = tid & 15;
    const int j    = cl & 7;
    const int half = cl >> 3;
    const int b    = b0 + (tid >> 4);

    const int rA = half * 16 + j;
    const int rB = half * 16 + 8 + j;

    const float NL2E = -1.4426950408889634f;
    const float GSC  = 2.0f * NL2E;
    const float sA   = half ? GSC : NL2E;
    const float sB   = NL2E;
    const float aselA = half ? 2.0f : GSC;
    const float bselA = half ? -1.0f : 0.0f;

    v2f Whk[8], Wik[8];
    float Wcp[8];
    #pragma unroll
    for (int s = 0; s < 8; ++s) {
        const int k = (j - s) & 7;
        Whk[s] = (v2f){Whh[rA * 8 + k] * sA, Whh[rB * 8 + k] * sB};
        if constexpr (PROJ)
            Wcp[s] = Wp[j * 16 + dcol + k] * 0.5f;
    }
    #pragma unroll
    for (int k = 0; k < 8; ++k)
        Wik[k] = (v2f){Wih[rA * 8 + k] * sA, Wih[rB * 8 + k] * sB};
    const v2f bpk = (v2f){bias[rA] * sA, bias[rB] * sB};

    const int start = (ST > 0) ? 0 : (T_LEN - 1);
    const float* xp = x + ((long)b * T_LEN + start) * 8;
    float* wp = nullptr;
    float* hp = nullptr;
    if constexpr (PROJ)  wp = y + ((long)b * T_LEN + start) * 8 + j;
    if constexpr (!PROJ) hp = H + ((long)b * T_LEN + start) * 8 + j;

    float sc = 0.0f, h = 0.0f;   // sc = GSC * c

    auto step = [&](v4f xa, v4f xb, bool doProj) {
        // input projection partials, two independent seeds (no h dependence)
        v2f ipA = bpk;
        ipA = __builtin_elementwise_fma(Wik[0], (v2f){xa.x, xa.x}, ipA);
        ipA = __builtin_elementwise_fma(Wik[1], (v2f){xa.y, xa.y}, ipA);
        ipA = __builtin_elementwise_fma(Wik[2], (v2f){xa.z, xa.z}, ipA);
        ipA = __builtin_elementwise_fma(Wik[3], (v2f){xa.w, xa.w}, ipA);
        v2f ipB = Wik[4] * (v2f){xb.x, xb.x};
        ipB = __builtin_elementwise_fma(Wik[5], (v2f){xb.y, xb.y}, ipB);
        ipB = __builtin_elementwise_fma(Wik[6], (v2f){xb.z, xb.z}, ipB);
        ipB = __builtin_elementwise_fma(Wik[7], (v2f){xb.w, xb.w}, ipB);

        // 7 independent VALU rotations of h (h_{t-1})
        float hr0 = h;
        float hr1 = rorN<1>(h);
        float hr2 = rorN<2>(h);
        float hr3 = rorN<3>(h);
        float hr4 = rorN<4>(h);
        float hr5 = rorN<5>(h);
        float hr6 = rorN<6>(h);
        float hr7 = rorN<7>(h);

        // hidden matvec: 4 depth-2 chains + depth-2 add tree
        v2f cA = __builtin_elementwise_fma(Whk[0], (v2f){hr0, hr0}, ipA);
        cA = __builtin_elementwise_fma(Whk[1], (v2f){hr1, hr1}, cA);
        v2f cB = __builtin_elementwise_fma(Whk[2], (v2f){hr2, hr2}, ipB);
        cB = __builtin_elementwise_fma(Whk[3], (v2f){hr3, hr3}, cB);
        v2f cC = Whk[4] * (v2f){hr4, hr4};
        cC = __builtin_elementwise_fma(Whk[5], (v2f){hr5, hr5}, cC);
        v2f cD = Whk[6] * (v2f){hr6, hr6};
        cD = __builtin_elementwise_fma(Whk[7], (v2f){hr7, hr7}, cD);
        const v2f z = (cA + cB) + (cC + cD);

        // fused output projection of h_{t-1} (fallback path only)
        if constexpr (PROJ) {
            if (doProj) {
                float pa = hr0 * Wcp[0];
                pa = fmaf(hr1, Wcp[1], pa);
                pa = fmaf(hr2, Wcp[2], pa);
                pa = fmaf(hr3, Wcp[3], pa);
                pa = fmaf(hr4, Wcp[4], pa);
                pa = fmaf(hr5, Wcp[5], pa);
                pa = fmaf(hr6, Wcp[6], pa);
                pa = fmaf(hr7, Wcp[7], pa);
                aatomic(wp, pa);
                wp += ST * 8;
            }
        }

        // activations: half0 vA = GSC*sigma(zi), half1 vA = tanh(zg);
        //              half0 vB = sigma(zf),     half1 vB = sigma(zo)
        const float vA = fmaf(frcp(1.0f + fexp2(z.x)), aselA, bselA);
        const float vB = frcp(1.0f + fexp2(z.y));

        // cross-half gate exchange (row_ror:8 swaps the two 8-lane halves);
        // i*g product is vA*ror8(vA) on BOTH halves (no select needed)
        const float pAx = rorN<8>(vA);
        const float pBx = rorN<8>(vB);
        const float gf = half ? pBx : vB;
        const float go = half ? vB  : pBx;

        sc = fmaf(gf, sc, vA * pAx);            // sc = GSC * c
        const float th = fmaf(frcp(1.0f + fexp2(sc)), 2.0f, -1.0f);
        h = go * th;

        if constexpr (!PROJ) {
            astore(hp, h);     // both halves store identical value: benign
            hp += ST * 8;
        }
    };

    // Named prefetch ring: 3 macros x 4 steps (2 x v4f per step).
    v4f A0, A1, A2, A3, A4, A5, A6, A7;
    v4f B0, B1, B2, B3, B4, B5, B6, B7;
    v4f C0, C1, C2, C3, C4, C5, C6, C7;

#define AREGS A0, A1, A2, A3, A4, A5, A6, A7
#define BREGS B0, B1, B2, B3, B4, B5, B6, B7
#define CREGS C0, C1, C2, C3, C4, C5, C6, C7

#define LOADM_I(P0, P1, P2, P3, P4, P5, P6, P7)                                \
    P0 = aload<0>(xp);            P1 = aload<16>(xp);                          \
    P2 = aload<ST * 32>(xp);      P3 = aload<ST * 32 + 16>(xp);                \
    P4 = aload<ST * 64>(xp);      P5 = aload<ST * 64 + 16>(xp);                \
    P6 = aload<ST * 96>(xp);      P7 = aload<ST * 96 + 16>(xp);                \
    xp += ST * 32;
#define LOADM(REGS) LOADM_I(REGS)

#define WAITM_I(N, P0, P1, P2, P3, P4, P5, P6, P7)                             \
    asm volatile("s_waitcnt vmcnt(" #N ")"                                     \
        : "+v"(P0), "+v"(P1), "+v"(P2), "+v"(P3),                              \
          "+v"(P4), "+v"(P5), "+v"(P6), "+v"(P7) :: "memory")
#define WAITM(N, REGS) WAITM_I(N, REGS)

#define MACRO4_I(P0, P1, P2, P3, P4, P5, P6, P7, FIRSTPROJ)                    \
    step(P0, P1, FIRSTPROJ);                                                   \
    step(P2, P3, true);                                                        \
    step(P4, P5, true);                                                        \
    step(P6, P7, true);
#define MACRO4(REGS, FIRSTPROJ) MACRO4_I(REGS, FIRSTPROJ)

    // drain compiler-issued (weight) loads so asm vm counts are exact
    asm volatile("s_waitcnt vmcnt(0)" ::: "memory");

    LOADM(AREGS)
    LOADM(BREGS)
    LOADM(CREGS)

    if constexpr (PROJ) {
        WAITM(16, AREGS); MACRO4(AREGS, false)
        LOADM(AREGS)
        WAITM(19, BREGS); MACRO4(BREGS, true)
        LOADM(BREGS)
        WAITM(23, CREGS); MACRO4(CREGS, true)
    } else {
        WAITM(16, AREGS); MACRO4(AREGS, true)
        LOADM(AREGS)
        WAITM(20, BREGS); MACRO4(BREGS, true)
        LOADM(BREGS)
        WAITM(24, CREGS); MACRO4(CREGS, true)
    }

    for (int i = 0; i < 339; ++i) {
        LOADM(CREGS) WAITM(24, AREGS); MACRO4(AREGS, true)
        LOADM(AREGS) WAITM(24, BREGS); MACRO4(BREGS, true)
        LOADM(BREGS) WAITM(24, CREGS); MACRO4(CREGS, true)
    }
    LOADM(CREGS)
    WAITM(24, AREGS); MACRO4(AREGS, true)
    LOADM(AREGS)
    WAITM(24, BREGS); MACRO4(BREGS, true)
    WAITM(16, CREGS); MACRO4(CREGS, true)
    WAITM(8,  AREGS); MACRO4(AREGS, true)

#undef LOADM
#undef LOADM_I
#undef MACRO4
#undef MACRO4_I
#undef WAITM
#undef WAITM_I
#undef AREGS
#undef BREGS
#undef CREGS

    if constexpr (PROJ) {
        float pa = h * Wcp[0];
        pa = fmaf(rorN<1>(h), Wcp[1], pa);
        pa = fmaf(rorN<2>(h), Wcp[2], pa);
        pa = fmaf(rorN<3>(h), Wcp[3], pa);
        pa = fmaf(rorN<4>(h), Wcp[4], pa);
        pa = fmaf(rorN<5>(h), Wcp[5], pa);
        pa = fmaf(rorN<6>(h), Wcp[6], pa);
        pa = fmaf(rorN<7>(h), Wcp[7], pa);
        aatomic(wp, pa);
    }
}

// Proven fused fallback (tier C): 4 cells/wave, 128 blocks.
__global__ __launch_bounds__(64, 1)
void lstm_rec_kernel(const float* __restrict__ x,
                     const float* __restrict__ WihF, const float* __restrict__ WhhF,
                     const float* __restrict__ bF,
                     const float* __restrict__ WihB, const float* __restrict__ WhhB,
                     const float* __restrict__ bB,
                     const float* __restrict__ Wp,
                     float* __restrict__ y)
{
    if (blockIdx.x < 64)
        rec_body<1,  true>(x, WihF, WhhF, bF, Wp, 0, y, nullptr, 4 * (int)blockIdx.x);
    else
        rec_body<-1, true>(x, WihB, WhhB, bB, Wp, 8, y, nullptr, 4 * ((int)blockIdx.x - 64));
}

// Tier-B' experiment: 2 cells/wave in lanes 0..31 (upper half exits),
// 256 blocks (128 fwd + 128 bwd). Identical per-wave instruction stream.
__global__ __launch_bounds__(64, 1)
void lstm_rec_np_kernel(const float* __restrict__ x,
                        const float* __restrict__ WihF, const float* __restrict__ WhhF,
                        const float* __restrict__ bF,
                        const float* __restrict__ WihB, const float* __restrict__ WhhB,
                        const float* __restrict__ bB,
                        float* __restrict__ Hf,
                        float* __restrict__ Hb)
{
    if (threadIdx.x >= 32) return;   // upper 32-lane half fully inactive
    const int r = (int)blockIdx.x;
    if (r < 128)
        rec_body<1,  false>(x, WihF, WhhF, bF, nullptr, 0, nullptr, Hf, 2 * r);
    else
        rec_body<-1, false>(x, WihB, WhhB, bB, nullptr, 0, nullptr, Hb, 2 * (r - 128));
}

extern "C" void kernel_launch(void* const* d_in, const int* in_sizes, int n_in,
                              void* d_out, int out_size, void* d_ws, size_t ws_size,
                              hipStream_t stream)
{
    const float* x     = (const float*)d_in[0];
    const float* Wih1f = (const float*)d_in[1];
    const float* Whh1f = (const float*)d_in[2];
    const float* b1f   = (const float*)d_in[3];
    const float* Wih1b = (const float*)d_in[4];
    const float* Whh1b = (const float*)d_in[5];
    const float* b1b   = (const float*)d_in[6];
    const float* Wih2f = (const float*)d_in[7];
    const float* Whh2f = (const float*)d_in[8];
    const float* b2f   = (const float*)d_in[9];
    const float* Wih2b = (const float*)d_in[10];
    const float* Whh2b = (const float*)d_in[11];
    const float* b2b   = (const float*)d_in[12];
    const float* W1    = (const float*)d_in[13];
    const float* bl1   = (const float*)d_in[14];
    const float* W2    = (const float*)d_in[15];
    const float* bl2   = (const float*)d_in[16];

    float* out = (float*)d_out;
    const int BT = B_SZ * T_LEN;
    const size_t MB32 = (size_t)32 * 1024 * 1024;

    if (ws_size >= 2 * MB32) {
        // Tier B': raw-h rec (2 cells/wave, lanes 0..31) + separate
        // projections. d_out borrowed for the backward-H buffer (dead by
        // the time the final in-place proj overwrites it).
        float* ws0 = (float*)d_ws;
        float* ws1 = (float*)((char*)d_ws + MB32);
        float* Hb  = out;

        lstm_rec_np_kernel<<<256, 64, 0, stream>>>(x, Wih1f, Whh1f, b1f,
                                                   Wih1b, Whh1b, b1b, ws0, Hb);
        proj_kernel<<<BT / 256, 256, 0, stream>>>(ws0, Hb, W1, bl1, ws1);
        lstm_rec_np_kernel<<<256, 64, 0, stream>>>(ws1, Wih2f, Whh2f, b2f,
                                                   Wih2b, Whh2b, b2b, ws0, Hb);
        proj_kernel<<<BT / 256, 256, 0, stream>>>(ws0, Hb, W2, bl2, out);
    } else {
        // Proven fallback (1098 us): fused atomic projection.
        float* y1 = (float*)d_ws;

        init_bias_kernel<<<BT / 256, 256, 0, stream>>>(bl1, bl2, y1, out);
        lstm_rec_kernel<<<128, 64, 0, stream>>>(x, Wih1f, Whh1f, b1f,
                                                Wih1b, Whh1b, b1b, W1, y1);
        lstm_rec_kernel<<<128, 64, 0, stream>>>(y1, Wih2f, Whh2f, b2f,
                                                Wih2b, Whh2b, b2b, W2, out);
    }
}

// Round 9
// 1069.392 us; speedup vs baseline: 1.2960x; 1.2960x over previous
//
#include <hip/hip_runtime.h>

#define T_LEN 4096
#define B_SZ  256

typedef float v2f __attribute__((ext_vector_type(2)));
typedef float v4f __attribute__((ext_vector_type(4)));

__device__ __forceinline__ float fexp2(float x) { return __builtin_amdgcn_exp2f(x); }
__device__ __forceinline__ float frcp(float x)  { return __builtin_amdgcn_rcpf(x); }

// DPP row_ror:S (S=1..15): lane l <- lane (l-S)&15 within its 16-lane row.
template<int S>
__device__ __forceinline__ float rorN(float v) {
    return __int_as_float(__builtin_amdgcn_update_dpp(
        0, __float_as_int(v), 0x120 + S, 0xf, 0xf, true));
}

// Inline-asm vm ops: RA cannot rematerialize an asm result (plain loads were
// re-emitted at uses, exposing full latency), and the asm vm stream keeps
// the outstanding-op counts for manual s_waitcnt exact.
template<int OFF>
__device__ __forceinline__ v4f aload(const float* p) {
    v4f r;
    asm volatile("global_load_dwordx4 %0, %1, off offset:%2"
                 : "=v"(r) : "v"(p), "i"(OFF) : "memory");
    return r;
}
__device__ __forceinline__ void aatomic(float* p, float v) {
    unsafeAtomicAdd(p, v);   // global_atomic_add_f32, no-return (result dead)
}
__device__ __forceinline__ void astore(float* p, float v) {
    asm volatile("global_store_dword %0, %1, off" :: "v"(p), "v"(v) : "memory");
}

// ---------------------------------------------------------------------------
// Fallback-path init: y1 <- bl1 broadcast, out <- bl2 broadcast.
// ---------------------------------------------------------------------------
__global__ void init_bias_kernel(const float* __restrict__ bl1,
                                 const float* __restrict__ bl2,
                                 float* __restrict__ y1,
                                 float* __restrict__ out)
{
    const long idx = (long)blockIdx.x * blockDim.x + threadIdx.x; // over B*T
    float4 a1 = make_float4(bl1[0], bl1[1], bl1[2], bl1[3]);
    float4 b1 = make_float4(bl1[4], bl1[5], bl1[6], bl1[7]);
    float4 a2 = make_float4(bl2[0], bl2[1], bl2[2], bl2[3]);
    float4 b2 = make_float4(bl2[4], bl2[5], bl2[6], bl2[7]);
    float4* y4 = (float4*)y1;
    float4* o4 = (float4*)out;
    y4[idx * 2 + 0] = a1;
    y4[idx * 2 + 1] = b1;
    o4[idx * 2 + 0] = a2;
    o4[idx * 2 + 1] = b2;
}

// ---------------------------------------------------------------------------
// Dense output projection y[b,t,:] = Hf@Wf^T + Hb@Wb^T + bl. One thread per
// (b,t) row. Hb/yo may ALIAS (final kernel runs in-place over d_out) -> no
// __restrict__ on those two; loads are emitted before stores (own row only).
// ---------------------------------------------------------------------------
__global__ void proj_kernel(const float* __restrict__ Hf,
                            const float* Hb,
                            const float* __restrict__ W,   // [8,16]
                            const float* __restrict__ bl,  // [8]
                            float* yo)
{
    const long idx = (long)blockIdx.x * blockDim.x + threadIdx.x; // over B*T
    const float4* f4 = (const float4*)(Hf + idx * 8);
    const float4* b4 = (const float4*)(Hb + idx * 8);
    float4 fa = f4[0], fb = f4[1];
    float4 ba = b4[0], bb = b4[1];
    float o[8];
    #pragma unroll
    for (int d = 0; d < 8; ++d) {
        float s = bl[d];
        s = fmaf(fa.x, W[d * 16 + 0], s);
        s = fmaf(fa.y, W[d * 16 + 1], s);
        s = fmaf(fa.z, W[d * 16 + 2], s);
        s = fmaf(fa.w, W[d * 16 + 3], s);
        s = fmaf(fb.x, W[d * 16 + 4], s);
        s = fmaf(fb.y, W[d * 16 + 5], s);
        s = fmaf(fb.z, W[d * 16 + 6], s);
        s = fmaf(fb.w, W[d * 16 + 7], s);
        s = fmaf(ba.x, W[d * 16 + 8], s);
        s = fmaf(ba.y, W[d * 16 + 9], s);
        s = fmaf(ba.z, W[d * 16 + 10], s);
        s = fmaf(ba.w, W[d * 16 + 11], s);
        s = fmaf(bb.x, W[d * 16 + 12], s);
        s = fmaf(bb.y, W[d * 16 + 13], s);
        s = fmaf(bb.z, W[d * 16 + 14], s);
        s = fmaf(bb.w, W[d * 16 + 15], s);
        o[d] = s;
    }
    float4* y4 = (float4*)(yo + idx * 8);
    y4[0] = make_float4(o[0], o[1], o[2], o[3]);
    y4[1] = make_float4(o[4], o[5], o[6], o[7]);
}

// ---------------------------------------------------------------------------
// Recurrence, one direction (ST=+1 fwd / -1 bwd). 16 lanes per cell, 4 cells
// per wave, 128 blocks x 64 threads (PROVEN best configuration; the R8
// 2-cell/wave half-skip experiment measured 0.72x per-wave issue rate —
// gfx950 does NOT skip fully-masked 32-lane halves). Lane cl: unit j=cl&7,
// half=cl>>3. Each lane computes TWO gate rows packed <2 x float>:
// half0 -> (i_j, f_j), half1 -> (g_j, o_j). h is period-8 replicated over
// the 16-lane row; DPP row_ror does the h broadcast. x arrives through an
// asm-load register ring (3 macros of 4 steps), lookahead 2 macros, exact
// manual s_waitcnt vmcnt(N).
//
// PROJ=true (fused fallback): atomic-add projection of h_{t-1}, ramp
// 16/19/23, steady 24, tail projects final h. PROJ=false (primary): one
// plain global_store_dword of h_t per step (both halves store identical
// value: benign duplicate), ramp 16/20/24, steady 24; projections run as
// separate memory-bound kernels (R6: -25 us/dispatch vs fused).
// ---------------------------------------------------------------------------
template<int ST, bool PROJ>
__device__ __forceinline__ void rec_body(
    const float* x, const float* Wih, const float* Whh, const float* bias,
    const float* Wp, int dcol, float* y, float* H, int b0)
{
    const int tid  = threadIdx.x;
    const int cl   = tid & 15;
    const int j    = cl & 7;
    const int half = cl >> 3;
    const int b    = b0 + (tid >> 4);

    const int rA = half * 16 + j;
    const int rB = half * 16 + 8 + j;

    const float NL2E = -1.4426950408889634f;
    const float GSC  = 2.0f * NL2E;
    const float sA   = half ? GSC : NL2E;
    const float sB   = NL2E;
    const float aselA = half ? 2.0f : GSC;
    const float bselA = half ? -1.0f : 0.0f;

    v2f Whk[8], Wik[8];
    float Wcp[8];
    #pragma unroll
    for (int s = 0; s < 8; ++s) {
        const int k = (j - s) & 7;
        Whk[s] = (v2f){Whh[rA * 8 + k] * sA, Whh[rB * 8 + k] * sB};
        if constexpr (PROJ)
            Wcp[s] = Wp[j * 16 + dcol + k] * 0.5f;
    }
    #pragma unroll
    for (int k = 0; k < 8; ++k)
        Wik[k] = (v2f){Wih[rA * 8 + k] * sA, Wih[rB * 8 + k] * sB};
    const v2f bpk = (v2f){bias[rA] * sA, bias[rB] * sB};

    const int start = (ST > 0) ? 0 : (T_LEN - 1);
    const float* xp = x + ((long)b * T_LEN + start) * 8;
    float* wp = nullptr;
    float* hp = nullptr;
    if constexpr (PROJ)  wp = y + ((long)b * T_LEN + start) * 8 + j;
    if constexpr (!PROJ) hp = H + ((long)b * T_LEN + start) * 8 + j;

    float sc = 0.0f, h = 0.0f;   // sc = GSC * c

    auto step = [&](v4f xa, v4f xb, bool doProj) {
        // input projection partials, two independent seeds (no h dependence)
        v2f ipA = bpk;
        ipA = __builtin_elementwise_fma(Wik[0], (v2f){xa.x, xa.x}, ipA);
        ipA = __builtin_elementwise_fma(Wik[1], (v2f){xa.y, xa.y}, ipA);
        ipA = __builtin_elementwise_fma(Wik[2], (v2f){xa.z, xa.z}, ipA);
        ipA = __builtin_elementwise_fma(Wik[3], (v2f){xa.w, xa.w}, ipA);
        v2f ipB = Wik[4] * (v2f){xb.x, xb.x};
        ipB = __builtin_elementwise_fma(Wik[5], (v2f){xb.y, xb.y}, ipB);
        ipB = __builtin_elementwise_fma(Wik[6], (v2f){xb.z, xb.z}, ipB);
        ipB = __builtin_elementwise_fma(Wik[7], (v2f){xb.w, xb.w}, ipB);

        // 7 independent VALU rotations of h (h_{t-1})
        float hr0 = h;
        float hr1 = rorN<1>(h);
        float hr2 = rorN<2>(h);
        float hr3 = rorN<3>(h);
        float hr4 = rorN<4>(h);
        float hr5 = rorN<5>(h);
        float hr6 = rorN<6>(h);
        float hr7 = rorN<7>(h);

        // hidden matvec: 4 depth-2 chains + depth-2 add tree
        v2f cA = __builtin_elementwise_fma(Whk[0], (v2f){hr0, hr0}, ipA);
        cA = __builtin_elementwise_fma(Whk[1], (v2f){hr1, hr1}, cA);
        v2f cB = __builtin_elementwise_fma(Whk[2], (v2f){hr2, hr2}, ipB);
        cB = __builtin_elementwise_fma(Whk[3], (v2f){hr3, hr3}, cB);
        v2f cC = Whk[4] * (v2f){hr4, hr4};
        cC = __builtin_elementwise_fma(Whk[5], (v2f){hr5, hr5}, cC);
        v2f cD = Whk[6] * (v2f){hr6, hr6};
        cD = __builtin_elementwise_fma(Whk[7], (v2f){hr7, hr7}, cD);
        const v2f z = (cA + cB) + (cC + cD);

        // fused output projection of h_{t-1} (fallback path only)
        if constexpr (PROJ) {
            if (doProj) {
                float pa = hr0 * Wcp[0];
                pa = fmaf(hr1, Wcp[1], pa);
                pa = fmaf(hr2, Wcp[2], pa);
                pa = fmaf(hr3, Wcp[3], pa);
                pa = fmaf(hr4, Wcp[4], pa);
                pa = fmaf(hr5, Wcp[5], pa);
                pa = fmaf(hr6, Wcp[6], pa);
                pa = fmaf(hr7, Wcp[7], pa);
                aatomic(wp, pa);
                wp += ST * 8;
            }
        }

        // activations: half0 vA = GSC*sigma(zi), half1 vA = tanh(zg);
        //              half0 vB = sigma(zf),     half1 vB = sigma(zo)
        const float vA = fmaf(frcp(1.0f + fexp2(z.x)), aselA, bselA);
        const float vB = frcp(1.0f + fexp2(z.y));

        // cross-half gate exchange (row_ror:8 swaps the two 8-lane halves);
        // i*g product is vA*ror8(vA) on BOTH halves (no select needed)
        const float pAx = rorN<8>(vA);
        const float pBx = rorN<8>(vB);
        const float gf = half ? pBx : vB;
        const float go = half ? vB  : pBx;

        sc = fmaf(gf, sc, vA * pAx);            // sc = GSC * c
        const float th = fmaf(frcp(1.0f + fexp2(sc)), 2.0f, -1.0f);
        h = go * th;

        if constexpr (!PROJ) {
            astore(hp, h);     // both halves store identical value: benign
            hp += ST * 8;
        }
    };

    // Named prefetch ring: 3 macros x 4 steps (2 x v4f per step).
    v4f A0, A1, A2, A3, A4, A5, A6, A7;
    v4f B0, B1, B2, B3, B4, B5, B6, B7;
    v4f C0, C1, C2, C3, C4, C5, C6, C7;

#define AREGS A0, A1, A2, A3, A4, A5, A6, A7
#define BREGS B0, B1, B2, B3, B4, B5, B6, B7
#define CREGS C0, C1, C2, C3, C4, C5, C6, C7

#define LOADM_I(P0, P1, P2, P3, P4, P5, P6, P7)                                \
    P0 = aload<0>(xp);            P1 = aload<16>(xp);                          \
    P2 = aload<ST * 32>(xp);      P3 = aload<ST * 32 + 16>(xp);                \
    P4 = aload<ST * 64>(xp);      P5 = aload<ST * 64 + 16>(xp);                \
    P6 = aload<ST * 96>(xp);      P7 = aload<ST * 96 + 16>(xp);                \
    xp += ST * 32;
#define LOADM(REGS) LOADM_I(REGS)

#define WAITM_I(N, P0, P1, P2, P3, P4, P5, P6, P7)                             \
    asm volatile("s_waitcnt vmcnt(" #N ")"                                     \
        : "+v"(P0), "+v"(P1), "+v"(P2), "+v"(P3),                              \
          "+v"(P4), "+v"(P5), "+v"(P6), "+v"(P7) :: "memory")
#define WAITM(N, REGS) WAITM_I(N, REGS)

#define MACRO4_I(P0, P1, P2, P3, P4, P5, P6, P7, FIRSTPROJ)                    \
    step(P0, P1, FIRSTPROJ);                                                   \
    step(P2, P3, true);                                                        \
    step(P4, P5, true);                                                        \
    step(P6, P7, true);
#define MACRO4(REGS, FIRSTPROJ) MACRO4_I(REGS, FIRSTPROJ)

    // drain compiler-issued (weight) loads so asm vm counts are exact
    asm volatile("s_waitcnt vmcnt(0)" ::: "memory");

    LOADM(AREGS)
    LOADM(BREGS)
    LOADM(CREGS)

    if constexpr (PROJ) {
        WAITM(16, AREGS); MACRO4(AREGS, false)
        LOADM(AREGS)
        WAITM(19, BREGS); MACRO4(BREGS, true)
        LOADM(BREGS)
        WAITM(23, CREGS); MACRO4(CREGS, true)
    } else {
        WAITM(16, AREGS); MACRO4(AREGS, true)
        LOADM(AREGS)
        WAITM(20, BREGS); MACRO4(BREGS, true)
        LOADM(BREGS)
        WAITM(24, CREGS); MACRO4(CREGS, true)
    }

    for (int i = 0; i < 339; ++i) {
        LOADM(CREGS) WAITM(24, AREGS); MACRO4(AREGS, true)
        LOADM(AREGS) WAITM(24, BREGS); MACRO4(BREGS, true)
        LOADM(BREGS) WAITM(24, CREGS); MACRO4(CREGS, true)
    }
    LOADM(CREGS)
    WAITM(24, AREGS); MACRO4(AREGS, true)
    LOADM(AREGS)
    WAITM(24, BREGS); MACRO4(BREGS, true)
    WAITM(16, CREGS); MACRO4(CREGS, true)
    WAITM(8,  AREGS); MACRO4(AREGS, true)

#undef LOADM
#undef LOADM_I
#undef MACRO4
#undef MACRO4_I
#undef WAITM
#undef WAITM_I
#undef AREGS
#undef BREGS
#undef CREGS

    if constexpr (PROJ) {
        float pa = h * Wcp[0];
        pa = fmaf(rorN<1>(h), Wcp[1], pa);
        pa = fmaf(rorN<2>(h), Wcp[2], pa);
        pa = fmaf(rorN<3>(h), Wcp[3], pa);
        pa = fmaf(rorN<4>(h), Wcp[4], pa);
        pa = fmaf(rorN<5>(h), Wcp[5], pa);
        pa = fmaf(rorN<6>(h), Wcp[6], pa);
        pa = fmaf(rorN<7>(h), Wcp[7], pa);
        aatomic(wp, pa);
    }
}

// Proven fused fallback (tier C): 4 cells/wave, 128 blocks.
__global__ __launch_bounds__(64, 1)
void lstm_rec_kernel(const float* __restrict__ x,
                     const float* __restrict__ WihF, const float* __restrict__ WhhF,
                     const float* __restrict__ bF,
                     const float* __restrict__ WihB, const float* __restrict__ WhhB,
                     const float* __restrict__ bB,
                     const float* __restrict__ Wp,
                     float* __restrict__ y)
{
    if (blockIdx.x < 64)
        rec_body<1,  true>(x, WihF, WhhF, bF, Wp, 0, y, nullptr, 4 * (int)blockIdx.x);
    else
        rec_body<-1, true>(x, WihB, WhhB, bB, Wp, 8, y, nullptr, 4 * ((int)blockIdx.x - 64));
}

// Primary (tier B, proven 1068 us): raw-h store, 4 cells/wave, 128 blocks.
__global__ __launch_bounds__(64, 1)
void lstm_rec_np_kernel(const float* __restrict__ x,
                        const float* __restrict__ WihF, const float* __restrict__ WhhF,
                        const float* __restrict__ bF,
                        const float* __restrict__ WihB, const float* __restrict__ WhhB,
                        const float* __restrict__ bB,
                        float* __restrict__ Hf,
                        float* __restrict__ Hb)
{
    if (blockIdx.x < 64)
        rec_body<1,  false>(x, WihF, WhhF, bF, nullptr, 0, nullptr, Hf, 4 * (int)blockIdx.x);
    else
        rec_body<-1, false>(x, WihB, WhhB, bB, nullptr, 0, nullptr, Hb, 4 * ((int)blockIdx.x - 64));
}

extern "C" void kernel_launch(void* const* d_in, const int* in_sizes, int n_in,
                              void* d_out, int out_size, void* d_ws, size_t ws_size,
                              hipStream_t stream)
{
    const float* x     = (const float*)d_in[0];
    const float* Wih1f = (const float*)d_in[1];
    const float* Whh1f = (const float*)d_in[2];
    const float* b1f   = (const float*)d_in[3];
    const float* Wih1b = (const float*)d_in[4];
    const float* Whh1b = (const float*)d_in[5];
    const float* b1b   = (const float*)d_in[6];
    const float* Wih2f = (const float*)d_in[7];
    const float* Whh2f = (const float*)d_in[8];
    const float* b2f   = (const float*)d_in[9];
    const float* Wih2b = (const float*)d_in[10];
    const float* Whh2b = (const float*)d_in[11];
    const float* b2b   = (const float*)d_in[12];
    const float* W1    = (const float*)d_in[13];
    const float* bl1   = (const float*)d_in[14];
    const float* W2    = (const float*)d_in[15];
    const float* bl2   = (const float*)d_in[16];

    float* out = (float*)d_out;
    const int BT = B_SZ * T_LEN;
    const size_t MB32 = (size_t)32 * 1024 * 1024;

    if (ws_size >= 2 * MB32) {
        // Tier B (proven 1068 us): raw-h rec + separate projections.
        // d_out borrowed for the backward-H buffer (dead by the time the
        // final in-place proj overwrites it).
        float* ws0 = (float*)d_ws;
        float* ws1 = (float*)((char*)d_ws + MB32);
        float* Hb  = out;

        lstm_rec_np_kernel<<<128, 64, 0, stream>>>(x, Wih1f, Whh1f, b1f,
                                                   Wih1b, Whh1b, b1b, ws0, Hb);
        proj_kernel<<<BT / 256, 256, 0, stream>>>(ws0, Hb, W1, bl1, ws1);
        lstm_rec_np_kernel<<<128, 64, 0, stream>>>(ws1, Wih2f, Whh2f, b2f,
                                                   Wih2b, Whh2b, b2b, ws0, Hb);
        proj_kernel<<<BT / 256, 256, 0, stream>>>(ws0, Hb, W2, bl2, out);
    } else {
        // Proven fallback (1098 us): fused atomic projection.
        float* y1 = (float*)d_ws;

        init_bias_kernel<<<BT / 256, 256, 0, stream>>>(bl1, bl2, y1, out);
        lstm_rec_kernel<<<128, 64, 0, stream>>>(x, Wih1f, Whh1f, b1f,
                                                Wih1b, Whh1b, b1b, W1, y1);
        lstm_rec_kernel<<<128, 64, 0, stream>>>(y1, Wih2f, Whh2f, b2f,
                                                Wih2b, Whh2b, b2b, W2, out);
    }
}